// Round 12
// baseline (151.921 us; speedup 1.0000x reference)
//
#include <hip/hip_runtime.h>
#include <hip/hip_cooperative_groups.h>

namespace cg = cooperative_groups;

// Problem constants (match reference)
#define BB 64
#define LL 1500
#define DD 768
#define TT 240000
#define BIN 160          // raw-time positions per bin
#define NCH 30           // L-chunks for deterministic two-stage reduce
#define LCH 50           // LL / NCH
#define TWO_D 1536
#define NJ1 8            // j-tile per fc1 phase block
#define ND2 4            // d-tile per fc2 phase block

// ---------------- workspace layout (bytes) ----------------
#define OFF_PARTIAL 0          // BB*NCH*DD floats (5,898,240 B)
#define OFF_LEN     5898240    // BB ints (256 B)
#define OFF_MEANT   5898496    // DD*BB floats     (196,608 B)  meanT[d][b]
#define OFF_HT      6095104    // TWO_D*BB floats  (393,216 B)  hT[j][b]
#define OFF_RAW     6488320    // BB*DD floats     (196,608 B)  raw[b][d]

// k_partial: fused length-search + embedding streamer (unchanged from R11).
__global__ __launch_bounds__(192) void k_partial(const float* __restrict__ emb,
                                                 const unsigned int* __restrict__ mask,
                                                 float* __restrict__ partial,
                                                 int* __restrict__ lenb) {
    int w = blockIdx.x;                  // 0..BB*NCH-1, c fastest
    int b = w / NCH, c = w % NCH, t = threadIdx.x;
    int lane = t & 63;

    // wave-parallel 64-ary search for len[b] (mask is a monotone suffix)
    int lo = TT / 2, hi = TT;
    while (hi > lo) {
        int step = (hi - lo + 63) / 64;  // ceil
        int p = lo + lane * step;
        unsigned int v = (p >= hi) ? 1u : mask[(size_t)b * TT + p];
        unsigned long long bal = __ballot(v != 0u);
        int f = __ffsll((unsigned long long)bal) - 1;   // first 'True' lane
        if (f < 0) {
            lo = lo + 63 * step + 1;
            if (lo > hi) lo = hi;
        } else {
            int new_hi = lo + f * step;
            int new_lo = (f == 0) ? lo : (lo + (f - 1) * step + 1);
            lo = new_lo;
            hi = (new_hi < hi) ? new_hi : hi;
        }
    }
    int len = lo;
    if (c == 0 && t == 0) lenb[b] = len;

    int fl = len / BIN;                  // total valid bins for this b
    int n = fl - c * LCH;
    n = (n < 0) ? 0 : ((n > LCH) ? LCH : n);

    float* pout = partial + (size_t)w * DD + 4 * t;
    if (n == 0) {
        float4 z = {0.f, 0.f, 0.f, 0.f};
        *(float4*)pout = z;
        return;
    }

    const float* ebase = emb + ((size_t)b * LL + c * LCH) * DD + 4 * t;
    float4 acc = {0.f, 0.f, 0.f, 0.f};
    if (n == LCH) {
        for (int i0 = 0; i0 < LCH; i0 += 10) {
#pragma unroll
            for (int j = 0; j < 10; ++j) {
                float4 v = *(const float4*)(ebase + (size_t)(i0 + j) * DD);
                acc.x += v.x; acc.y += v.y; acc.z += v.z; acc.w += v.w;
            }
        }
    } else {
        int nr = ((n + 4) / 5) * 5;
        for (int i0 = 0; i0 < nr; i0 += 5) {
#pragma unroll
            for (int j = 0; j < 5; ++j) {
                int i = i0 + j;
                float4 v = *(const float4*)(ebase + (size_t)i * DD);
                float f = (i < n) ? 1.0f : 0.0f;
                acc.x = fmaf(f, v.x, acc.x);
                acc.y = fmaf(f, v.y, acc.y);
                acc.z = fmaf(f, v.z, acc.z);
                acc.w = fmaf(f, v.w, acc.w);
            }
        }
    }
    *(float4*)pout = acc;
}

// k_tail: cooperative fusion of meanT -> fc1 -> fc2 -> norm with grid syncs.
// 192 blocks x 256 threads (co-resident on 256 CUs). Phase bodies identical
// to the R11 kernels -> same arithmetic order, same results.
__global__ __launch_bounds__(256) void k_tail(const float* __restrict__ partial,
                                              const int* __restrict__ lenb,
                                              const float* __restrict__ W1,
                                              const float* __restrict__ W2,
                                              float* __restrict__ meanT,
                                              float* __restrict__ hT,
                                              float* __restrict__ raw,
                                              float* __restrict__ out) {
    cg::grid_group grid = cg::this_grid();
    __shared__ float shbuf[4 * NJ1 * BB];        // 8 KB, reused per phase
    int wid = threadIdx.x >> 6, lane = threadIdx.x & 63;

    // ---------------- phase 1: meanT[d][b] ----------------
    {
        int idx = blockIdx.x * 256 + threadIdx.x;        // 0..49151
        if (idx < BB * (DD / 4)) {                       // 12288 active
            int b = idx / (DD / 4), q = idx % (DD / 4);
            float cnt = (float)(lenb[b] / BIN);          // >= 750 > 0
            const float4* pb = (const float4*)(partial + (size_t)b * NCH * DD) + q;
            float4 s = {0.f, 0.f, 0.f, 0.f};
#pragma unroll 10
            for (int c = 0; c < NCH; ++c) {
                float4 v = pb[(size_t)c * (DD / 4)];
                s.x += v.x; s.y += v.y; s.z += v.z; s.w += v.w;
            }
            float inv = 1.0f / cnt;
            int d = 4 * q;
            meanT[(size_t)(d + 0) * BB + b] = s.x * inv;
            meanT[(size_t)(d + 1) * BB + b] = s.y * inv;
            meanT[(size_t)(d + 2) * BB + b] = s.z * inv;
            meanT[(size_t)(d + 3) * BB + b] = s.w * inv;
        }
    }
    grid.sync();

    // ---------------- phase 2: hT[j][b] = relu(W1 . mean) ----------------
    {
        int j0 = blockIdx.x * NJ1;                       // 192 blocks x 8 j
        const float* mp    = meanT + (size_t)(wid * (DD / 4)) * BB + lane;
        const float* wbase = W1 + (size_t)j0 * DD + wid * (DD / 4);
        float acc[NJ1] = {0.f, 0.f, 0.f, 0.f, 0.f, 0.f, 0.f, 0.f};
        for (int k = 0; k < DD / 4; k += 8) {            // 24 steps
            float m0 = mp[(size_t)(k + 0) * BB];
            float m1 = mp[(size_t)(k + 1) * BB];
            float m2 = mp[(size_t)(k + 2) * BB];
            float m3 = mp[(size_t)(k + 3) * BB];
            float m4 = mp[(size_t)(k + 4) * BB];
            float m5 = mp[(size_t)(k + 5) * BB];
            float m6 = mp[(size_t)(k + 6) * BB];
            float m7 = mp[(size_t)(k + 7) * BB];
#pragma unroll
            for (int jj = 0; jj < NJ1; ++jj) {
                const float* wr = wbase + (size_t)jj * DD + k;
                float4 wa = *(const float4*)(wr);
                float4 wb = *(const float4*)(wr + 4);
                float a = acc[jj];
                a = fmaf(wa.x, m0, a); a = fmaf(wa.y, m1, a);
                a = fmaf(wa.z, m2, a); a = fmaf(wa.w, m3, a);
                a = fmaf(wb.x, m4, a); a = fmaf(wb.y, m5, a);
                a = fmaf(wb.z, m6, a); a = fmaf(wb.w, m7, a);
                acc[jj] = a;
            }
        }
        float (*sh)[NJ1][BB] = (float (*)[NJ1][BB])shbuf;
#pragma unroll
        for (int jj = 0; jj < NJ1; ++jj) sh[wid][jj][lane] = acc[jj];
        __syncthreads();
        for (int idx = threadIdx.x; idx < NJ1 * BB; idx += 256) {
            int jj = idx >> 6, b2 = idx & 63;
            float r = (sh[0][jj][b2] + sh[1][jj][b2]) + (sh[2][jj][b2] + sh[3][jj][b2]);
            hT[(size_t)(j0 + jj) * BB + b2] = fmaxf(r, 0.0f);
        }
    }
    grid.sync();

    // ---------------- phase 3: raw[b][d] = W2 . h ----------------
    {
        int d0 = blockIdx.x * ND2;                       // 192 blocks x 4 d
        const float* hp    = hT + (size_t)(wid * (TWO_D / 4)) * BB + lane;
        const float* wbase = W2 + (size_t)d0 * TWO_D + wid * (TWO_D / 4);
        float acc[ND2] = {0.f, 0.f, 0.f, 0.f};
        for (int k = 0; k < TWO_D / 4; k += 8) {         // 48 steps
            float h0 = hp[(size_t)(k + 0) * BB];
            float h1 = hp[(size_t)(k + 1) * BB];
            float h2 = hp[(size_t)(k + 2) * BB];
            float h3 = hp[(size_t)(k + 3) * BB];
            float h4 = hp[(size_t)(k + 4) * BB];
            float h5 = hp[(size_t)(k + 5) * BB];
            float h6 = hp[(size_t)(k + 6) * BB];
            float h7 = hp[(size_t)(k + 7) * BB];
#pragma unroll
            for (int dd = 0; dd < ND2; ++dd) {
                const float* wr = wbase + (size_t)dd * TWO_D + k;
                float4 wa = *(const float4*)(wr);
                float4 wb = *(const float4*)(wr + 4);
                float a = acc[dd];
                a = fmaf(wa.x, h0, a); a = fmaf(wa.y, h1, a);
                a = fmaf(wa.z, h2, a); a = fmaf(wa.w, h3, a);
                a = fmaf(wb.x, h4, a); a = fmaf(wb.y, h5, a);
                a = fmaf(wb.z, h6, a); a = fmaf(wb.w, h7, a);
                acc[dd] = a;
            }
        }
        float (*sh)[ND2][BB] = (float (*)[ND2][BB])shbuf;
        __syncthreads();                                 // shbuf reuse guard
#pragma unroll
        for (int dd = 0; dd < ND2; ++dd) sh[wid][dd][lane] = acc[dd];
        __syncthreads();
        {
            int idx = threadIdx.x;                       // ND2*BB == 256
            int dd = idx >> 6, b2 = idx & 63;
            float r = (sh[0][dd][b2] + sh[1][dd][b2]) + (sh[2][dd][b2] + sh[3][dd][b2]);
            raw[(size_t)b2 * DD + d0 + dd] = r;
        }
    }
    grid.sync();

    // ---------------- phase 4: out[b,:] = raw[b,:] / ||raw[b,:]|| ----------------
    if (blockIdx.x < BB) {
        int b = blockIdx.x, t = threadIdx.x;
        float v0 = raw[b * DD + t];
        float v1 = raw[b * DD + 256 + t];
        float v2 = raw[b * DD + 512 + t];
        float s = v0 * v0 + v1 * v1 + v2 * v2;
        for (int off = 32; off; off >>= 1) s += __shfl_down(s, off);
        float* sh = shbuf;                               // 4 floats + 1
        __syncthreads();
        if ((t & 63) == 0) sh[t >> 6] = s;
        __syncthreads();
        if (t == 0) sh[4] = 1.0f / sqrtf(sh[0] + sh[1] + sh[2] + sh[3]);
        __syncthreads();
        float inv = sh[4];
        out[b * DD + t]       = v0 * inv;
        out[b * DD + 256 + t] = v1 * inv;
        out[b * DD + 512 + t] = v2 * inv;
    }
}

extern "C" void kernel_launch(void* const* d_in, const int* in_sizes, int n_in,
                              void* d_out, int out_size, void* d_ws, size_t ws_size,
                              hipStream_t stream) {
    const float* emb         = (const float*)d_in[0];          // (B,L,D) f32
    const float* W1          = (const float*)d_in[1];          // (2D,D) f32
    const float* W2          = (const float*)d_in[2];          // (D,2D) f32
    const unsigned int* mask = (const unsigned int*)d_in[3];   // (B,T) bool as int32

    char* ws = (char*)d_ws;
    float* partial = (float*)(ws + OFF_PARTIAL);
    int*   lenb    = (int*)(ws + OFF_LEN);
    float* meanT   = (float*)(ws + OFF_MEANT);
    float* hT      = (float*)(ws + OFF_HT);
    float* raw     = (float*)(ws + OFF_RAW);
    float* out     = (float*)d_out;

    k_partial<<<BB * NCH, 192, 0, stream>>>(emb, mask, partial, lenb);

    void* args[] = {&partial, &lenb, &W1, &W2, &meanT, &hT, &raw, &out};
    hipLaunchCooperativeKernel((void*)k_tail, dim3(192), dim3(256),
                               args, 0, stream);
}

// Round 13
// 147.190 us; speedup vs baseline: 1.0321x; 1.0321x over previous
//
#include <hip/hip_runtime.h>

// Problem constants (match reference)
#define BB 64
#define LL 1500
#define DD 768
#define TT 240000
#define BIN 160          // raw-time positions per bin
#define NCH 30           // L-chunks for deterministic two-stage reduce
#define LCH 50           // LL / NCH
#define TWO_D 1536
#define NJ1 8            // j-tile per fc1 phase block
#define ND2 4            // d-tile per fc2 phase block

// ---------------- workspace layout (bytes) ----------------
#define OFF_PARTIAL 0          // BB*NCH*DD floats (5,898,240 B)
#define OFF_LEN     5898240    // BB ints (256 B)
#define OFF_MEANT   5898496    // DD*BB floats     (196,608 B)  meanT[d][b]
#define OFF_HT      6095104    // TWO_D*BB floats  (393,216 B)  hT[j][b]
#define OFF_RAW     6488320    // BB*DD floats     (196,608 B)  raw[b][d]
#define OFF_CNT     6684928    // 64 B barrier counter (memset to 0 each call)

// k_partial: fused length-search + embedding streamer (unchanged from R11).
__global__ __launch_bounds__(192) void k_partial(const float* __restrict__ emb,
                                                 const unsigned int* __restrict__ mask,
                                                 float* __restrict__ partial,
                                                 int* __restrict__ lenb) {
    int w = blockIdx.x;                  // 0..BB*NCH-1, c fastest
    int b = w / NCH, c = w % NCH, t = threadIdx.x;
    int lane = t & 63;

    // wave-parallel 64-ary search for len[b] (mask is a monotone suffix)
    int lo = TT / 2, hi = TT;
    while (hi > lo) {
        int step = (hi - lo + 63) / 64;  // ceil
        int p = lo + lane * step;
        unsigned int v = (p >= hi) ? 1u : mask[(size_t)b * TT + p];
        unsigned long long bal = __ballot(v != 0u);
        int f = __ffsll((unsigned long long)bal) - 1;   // first 'True' lane
        if (f < 0) {
            lo = lo + 63 * step + 1;
            if (lo > hi) lo = hi;
        } else {
            int new_hi = lo + f * step;
            int new_lo = (f == 0) ? lo : (lo + (f - 1) * step + 1);
            lo = new_lo;
            hi = (new_hi < hi) ? new_hi : hi;
        }
    }
    int len = lo;
    if (c == 0 && t == 0) lenb[b] = len;

    int fl = len / BIN;                  // total valid bins for this b
    int n = fl - c * LCH;
    n = (n < 0) ? 0 : ((n > LCH) ? LCH : n);

    float* pout = partial + (size_t)w * DD + 4 * t;
    if (n == 0) {
        float4 z = {0.f, 0.f, 0.f, 0.f};
        *(float4*)pout = z;
        return;
    }

    const float* ebase = emb + ((size_t)b * LL + c * LCH) * DD + 4 * t;
    float4 acc = {0.f, 0.f, 0.f, 0.f};
    if (n == LCH) {
        for (int i0 = 0; i0 < LCH; i0 += 10) {
#pragma unroll
            for (int j = 0; j < 10; ++j) {
                float4 v = *(const float4*)(ebase + (size_t)(i0 + j) * DD);
                acc.x += v.x; acc.y += v.y; acc.z += v.z; acc.w += v.w;
            }
        }
    } else {
        int nr = ((n + 4) / 5) * 5;
        for (int i0 = 0; i0 < nr; i0 += 5) {
#pragma unroll
            for (int j = 0; j < 5; ++j) {
                int i = i0 + j;
                float4 v = *(const float4*)(ebase + (size_t)i * DD);
                float f = (i < n) ? 1.0f : 0.0f;
                acc.x = fmaf(f, v.x, acc.x);
                acc.y = fmaf(f, v.y, acc.y);
                acc.z = fmaf(f, v.z, acc.z);
                acc.w = fmaf(f, v.w, acc.w);
            }
        }
    }
    *(float4*)pout = acc;
}

// Manual grid barrier: all 192 blocks are co-resident (192 <= 256 CUs, 8KB
// LDS, modest VGPR). Monotone counter, device-scope release/acquire.
__device__ __forceinline__ void grid_barrier(unsigned int* cnt, unsigned int target) {
    __syncthreads();
    if (threadIdx.x == 0) {
        __threadfence();   // release: prior writes visible device-wide
        __hip_atomic_fetch_add(cnt, 1u, __ATOMIC_RELEASE, __HIP_MEMORY_SCOPE_AGENT);
        while (__hip_atomic_load(cnt, __ATOMIC_ACQUIRE, __HIP_MEMORY_SCOPE_AGENT) < target) {
            __builtin_amdgcn_s_sleep(8);
        }
        __threadfence();   // acquire: other blocks' writes visible to us
    }
    __syncthreads();
}

// k_tail: meanT -> fc1 -> fc2 -> norm, phases separated by manual barriers.
// Phase bodies identical to R12 (validated correct). Ordinary launch.
__global__ __launch_bounds__(256) void k_tail(const float* __restrict__ partial,
                                              const int* __restrict__ lenb,
                                              const float* __restrict__ W1,
                                              const float* __restrict__ W2,
                                              float* __restrict__ meanT,
                                              float* __restrict__ hT,
                                              float* __restrict__ raw,
                                              float* __restrict__ out,
                                              unsigned int* __restrict__ cnt) {
    __shared__ float shbuf[4 * NJ1 * BB];        // 8 KB, reused per phase
    int wid = threadIdx.x >> 6, lane = threadIdx.x & 63;

    // ---------------- phase 1: meanT[d][b] ----------------
    {
        int idx = blockIdx.x * 256 + threadIdx.x;        // 0..49151
        if (idx < BB * (DD / 4)) {                       // 12288 active
            int b = idx / (DD / 4), q = idx % (DD / 4);
            float cntv = (float)(lenb[b] / BIN);         // >= 750 > 0
            const float4* pb = (const float4*)(partial + (size_t)b * NCH * DD) + q;
            float4 s = {0.f, 0.f, 0.f, 0.f};
#pragma unroll 10
            for (int c = 0; c < NCH; ++c) {
                float4 v = pb[(size_t)c * (DD / 4)];
                s.x += v.x; s.y += v.y; s.z += v.z; s.w += v.w;
            }
            float inv = 1.0f / cntv;
            int d = 4 * q;
            meanT[(size_t)(d + 0) * BB + b] = s.x * inv;
            meanT[(size_t)(d + 1) * BB + b] = s.y * inv;
            meanT[(size_t)(d + 2) * BB + b] = s.z * inv;
            meanT[(size_t)(d + 3) * BB + b] = s.w * inv;
        }
    }
    grid_barrier(cnt, 192);

    // ---------------- phase 2: hT[j][b] = relu(W1 . mean) ----------------
    {
        int j0 = blockIdx.x * NJ1;                       // 192 blocks x 8 j
        const float* mp    = meanT + (size_t)(wid * (DD / 4)) * BB + lane;
        const float* wbase = W1 + (size_t)j0 * DD + wid * (DD / 4);
        float acc[NJ1] = {0.f, 0.f, 0.f, 0.f, 0.f, 0.f, 0.f, 0.f};
        for (int k = 0; k < DD / 4; k += 8) {            // 24 steps
            float m0 = mp[(size_t)(k + 0) * BB];
            float m1 = mp[(size_t)(k + 1) * BB];
            float m2 = mp[(size_t)(k + 2) * BB];
            float m3 = mp[(size_t)(k + 3) * BB];
            float m4 = mp[(size_t)(k + 4) * BB];
            float m5 = mp[(size_t)(k + 5) * BB];
            float m6 = mp[(size_t)(k + 6) * BB];
            float m7 = mp[(size_t)(k + 7) * BB];
#pragma unroll
            for (int jj = 0; jj < NJ1; ++jj) {
                const float* wr = wbase + (size_t)jj * DD + k;
                float4 wa = *(const float4*)(wr);
                float4 wb = *(const float4*)(wr + 4);
                float a = acc[jj];
                a = fmaf(wa.x, m0, a); a = fmaf(wa.y, m1, a);
                a = fmaf(wa.z, m2, a); a = fmaf(wa.w, m3, a);
                a = fmaf(wb.x, m4, a); a = fmaf(wb.y, m5, a);
                a = fmaf(wb.z, m6, a); a = fmaf(wb.w, m7, a);
                acc[jj] = a;
            }
        }
        float (*sh)[NJ1][BB] = (float (*)[NJ1][BB])shbuf;
#pragma unroll
        for (int jj = 0; jj < NJ1; ++jj) sh[wid][jj][lane] = acc[jj];
        __syncthreads();
        for (int idx = threadIdx.x; idx < NJ1 * BB; idx += 256) {
            int jj = idx >> 6, b2 = idx & 63;
            float r = (sh[0][jj][b2] + sh[1][jj][b2]) + (sh[2][jj][b2] + sh[3][jj][b2]);
            hT[(size_t)(j0 + jj) * BB + b2] = fmaxf(r, 0.0f);
        }
    }
    grid_barrier(cnt, 384);

    // ---------------- phase 3: raw[b][d] = W2 . h ----------------
    {
        int d0 = blockIdx.x * ND2;                       // 192 blocks x 4 d
        const float* hp    = hT + (size_t)(wid * (TWO_D / 4)) * BB + lane;
        const float* wbase = W2 + (size_t)d0 * TWO_D + wid * (TWO_D / 4);
        float acc[ND2] = {0.f, 0.f, 0.f, 0.f};
        for (int k = 0; k < TWO_D / 4; k += 8) {         // 48 steps
            float h0 = hp[(size_t)(k + 0) * BB];
            float h1 = hp[(size_t)(k + 1) * BB];
            float h2 = hp[(size_t)(k + 2) * BB];
            float h3 = hp[(size_t)(k + 3) * BB];
            float h4 = hp[(size_t)(k + 4) * BB];
            float h5 = hp[(size_t)(k + 5) * BB];
            float h6 = hp[(size_t)(k + 6) * BB];
            float h7 = hp[(size_t)(k + 7) * BB];
#pragma unroll
            for (int dd = 0; dd < ND2; ++dd) {
                const float* wr = wbase + (size_t)dd * TWO_D + k;
                float4 wa = *(const float4*)(wr);
                float4 wb = *(const float4*)(wr + 4);
                float a = acc[dd];
                a = fmaf(wa.x, h0, a); a = fmaf(wa.y, h1, a);
                a = fmaf(wa.z, h2, a); a = fmaf(wa.w, h3, a);
                a = fmaf(wb.x, h4, a); a = fmaf(wb.y, h5, a);
                a = fmaf(wb.z, h6, a); a = fmaf(wb.w, h7, a);
                acc[dd] = a;
            }
        }
        float (*sh)[ND2][BB] = (float (*)[ND2][BB])shbuf;
        __syncthreads();                                 // shbuf reuse guard
#pragma unroll
        for (int dd = 0; dd < ND2; ++dd) sh[wid][dd][lane] = acc[dd];
        __syncthreads();
        {
            int idx = threadIdx.x;                       // ND2*BB == 256
            int dd = idx >> 6, b2 = idx & 63;
            float r = (sh[0][dd][b2] + sh[1][dd][b2]) + (sh[2][dd][b2] + sh[3][dd][b2]);
            raw[(size_t)b2 * DD + d0 + dd] = r;
        }
    }
    grid_barrier(cnt, 576);

    // ---------------- phase 4: out[b,:] = raw[b,:] / ||raw[b,:]|| ----------------
    if (blockIdx.x < BB) {
        int b = blockIdx.x, t = threadIdx.x;
        float v0 = raw[b * DD + t];
        float v1 = raw[b * DD + 256 + t];
        float v2 = raw[b * DD + 512 + t];
        float s = v0 * v0 + v1 * v1 + v2 * v2;
        for (int off = 32; off; off >>= 1) s += __shfl_down(s, off);
        float* sh = shbuf;
        __syncthreads();
        if ((t & 63) == 0) sh[t >> 6] = s;
        __syncthreads();
        if (t == 0) sh[4] = 1.0f / sqrtf(sh[0] + sh[1] + sh[2] + sh[3]);
        __syncthreads();
        float inv = sh[4];
        out[b * DD + t]       = v0 * inv;
        out[b * DD + 256 + t] = v1 * inv;
        out[b * DD + 512 + t] = v2 * inv;
    }
}

extern "C" void kernel_launch(void* const* d_in, const int* in_sizes, int n_in,
                              void* d_out, int out_size, void* d_ws, size_t ws_size,
                              hipStream_t stream) {
    const float* emb         = (const float*)d_in[0];          // (B,L,D) f32
    const float* W1          = (const float*)d_in[1];          // (2D,D) f32
    const float* W2          = (const float*)d_in[2];          // (D,2D) f32
    const unsigned int* mask = (const unsigned int*)d_in[3];   // (B,T) bool as int32

    char* ws = (char*)d_ws;
    float* partial      = (float*)(ws + OFF_PARTIAL);
    int*   lenb         = (int*)(ws + OFF_LEN);
    float* meanT        = (float*)(ws + OFF_MEANT);
    float* hT           = (float*)(ws + OFF_HT);
    float* raw          = (float*)(ws + OFF_RAW);
    unsigned int* cnt   = (unsigned int*)(ws + OFF_CNT);
    float* out          = (float*)d_out;

    hipMemsetAsync(cnt, 0, 64, stream);   // barrier counter = 0 each call
    k_partial<<<BB * NCH, 192, 0, stream>>>(emb, mask, partial, lenb);
    void* dummy = nullptr; (void)dummy;
    k_tail<<<192, 256, 0, stream>>>(partial, lenb, W1, W2, meanT, hT, raw,
                                    out, cnt);
}

// Round 15
// 80.729 us; speedup vs baseline: 1.8819x; 1.8233x over previous
//
#include <hip/hip_runtime.h>

// Problem constants (match reference)
#define BB 64
#define LL 1500
#define DD 768
#define TT 240000
#define BIN 160          // raw-time positions per bin
#define NCH 25           // L-chunks for deterministic two-stage reduce
#define LCH 60           // LL / NCH (unroll-10 divides evenly)
#define TWO_D 1536
#define NJ1 8            // j-tile per fc1 block
#define ND2 4            // d-tile per fc2 block

// clang native vector type: __builtin_nontemporal_* accepts these
typedef float f32x4 __attribute__((ext_vector_type(4)));

// ---------------- workspace layout (bytes) ----------------
#define OFF_PARTIAL 0          // BB*NCH*DD floats (4,915,200 B)
#define OFF_LEN     4915200    // BB ints (256 B)
#define OFF_MEANT   4915456    // DD*BB floats     (196,608 B)  meanT[d][b]
#define OFF_HT      5112064    // TWO_D*BB floats  (393,216 B)  hT[j][b]
#define OFF_RAW     5505280    // BB*DD floats     (196,608 B)  raw[b][d]

// k_partial: fused length-search + embedding streamer (R11 structure).
// emb stream is zero-reuse -> nontemporal loads (no L2 fill); partial is
// write-once -> nontemporal store.
__global__ __launch_bounds__(192) void k_partial(const float* __restrict__ emb,
                                                 const unsigned int* __restrict__ mask,
                                                 float* __restrict__ partial,
                                                 int* __restrict__ lenb) {
    int w = blockIdx.x;                  // 0..BB*NCH-1, c fastest
    int b = w / NCH, c = w % NCH, t = threadIdx.x;
    int lane = t & 63;

    // wave-parallel 64-ary search for len[b] (mask is a monotone suffix)
    int lo = TT / 2, hi = TT;
    while (hi > lo) {
        int step = (hi - lo + 63) / 64;  // ceil
        int p = lo + lane * step;
        unsigned int v = (p >= hi) ? 1u : mask[(size_t)b * TT + p];
        unsigned long long bal = __ballot(v != 0u);
        int f = __ffsll((unsigned long long)bal) - 1;   // first 'True' lane
        if (f < 0) {
            lo = lo + 63 * step + 1;
            if (lo > hi) lo = hi;
        } else {
            int new_hi = lo + f * step;
            int new_lo = (f == 0) ? lo : (lo + (f - 1) * step + 1);
            lo = new_lo;
            hi = (new_hi < hi) ? new_hi : hi;
        }
    }
    int len = lo;
    if (c == 0 && t == 0) lenb[b] = len;

    int fl = len / BIN;                  // total valid bins for this b
    int n = fl - c * LCH;
    n = (n < 0) ? 0 : ((n > LCH) ? LCH : n);

    float* pout = partial + (size_t)w * DD + 4 * t;
    if (n == 0) {
        f32x4 z = {0.f, 0.f, 0.f, 0.f};
        __builtin_nontemporal_store(z, (f32x4*)pout);
        return;
    }

    const float* ebase = emb + ((size_t)b * LL + c * LCH) * DD + 4 * t;
    f32x4 acc = {0.f, 0.f, 0.f, 0.f};
    if (n == LCH) {
        // fast path: all 60 rows valid -- pure streaming nontemporal adds
        for (int i0 = 0; i0 < LCH; i0 += 10) {
#pragma unroll
            for (int j = 0; j < 10; ++j) {       // 10 loads in flight
                f32x4 v = __builtin_nontemporal_load(
                    (const f32x4*)(ebase + (size_t)(i0 + j) * DD));
                acc += v;
            }
        }
    } else {
        // boundary chunk (<=1 per b): flag-FMA, rounded to multiple of 5
        int nr = ((n + 4) / 5) * 5;
        for (int i0 = 0; i0 < nr; i0 += 5) {
#pragma unroll
            for (int j = 0; j < 5; ++j) {
                int i = i0 + j;
                f32x4 v = __builtin_nontemporal_load(
                    (const f32x4*)(ebase + (size_t)i * DD));
                float f = (i < n) ? 1.0f : 0.0f; // {0,1} -> exact
                acc.x = fmaf(f, v.x, acc.x);
                acc.y = fmaf(f, v.y, acc.y);
                acc.z = fmaf(f, v.z, acc.z);
                acc.w = fmaf(f, v.w, acc.w);
            }
        }
    }
    __builtin_nontemporal_store(acc, (f32x4*)pout);
}

// meanT[d][b] = (sum_c partial[b,c,d]) / (len[b]/BIN)
// 192 blocks (3 slabs per b) x 64 threads; thread owns one float4 column.
// partial is read-once -> nontemporal loads.
__global__ void k_meanT(const float* __restrict__ partial,
                        const int* __restrict__ lenb,
                        float* __restrict__ meanT) {
    int bid = blockIdx.x;
    int b = bid / 3, slab = bid % 3;
    int q = slab * 64 + threadIdx.x;         // float4 index over d (0..191)
    float cnt = (float)(lenb[b] / BIN);      // >= 750 > 0 by construction
    const f32x4* pb = (const f32x4*)(partial + (size_t)b * NCH * DD) + q;
    f32x4 s = {0.f, 0.f, 0.f, 0.f};
#pragma unroll 5
    for (int c = 0; c < NCH; ++c) {
        f32x4 v = __builtin_nontemporal_load(pb + (size_t)c * (DD / 4));
        s += v;
    }
    float inv = 1.0f / cnt;
    int d = 4 * q;
    meanT[(size_t)(d + 0) * BB + b] = s.x * inv;
    meanT[(size_t)(d + 1) * BB + b] = s.y * inv;
    meanT[(size_t)(d + 2) * BB + b] = s.z * inv;
    meanT[(size_t)(d + 3) * BB + b] = s.w * inv;
}

// hT[j][b] = relu( sum_d meanT[d][b] * W1[j,d] )
// 192 blocks x 8 j's. 4 waves split d-range (192 each); lane = b.
__global__ __launch_bounds__(256) void k_fc1T(const float* __restrict__ meanT,
                                              const float* __restrict__ W1,
                                              float* __restrict__ hT) {
    int j0 = blockIdx.x * NJ1;
    int wid = threadIdx.x >> 6, lane = threadIdx.x & 63;
    const float* mp    = meanT + (size_t)(wid * (DD / 4)) * BB + lane;
    const float* wbase = W1 + (size_t)j0 * DD + wid * (DD / 4);
    float acc[NJ1] = {0.f, 0.f, 0.f, 0.f, 0.f, 0.f, 0.f, 0.f};
    for (int k = 0; k < DD / 4; k += 8) {        // 24 steps
        float m0 = mp[(size_t)(k + 0) * BB];
        float m1 = mp[(size_t)(k + 1) * BB];
        float m2 = mp[(size_t)(k + 2) * BB];
        float m3 = mp[(size_t)(k + 3) * BB];
        float m4 = mp[(size_t)(k + 4) * BB];
        float m5 = mp[(size_t)(k + 5) * BB];
        float m6 = mp[(size_t)(k + 6) * BB];
        float m7 = mp[(size_t)(k + 7) * BB];
#pragma unroll
        for (int jj = 0; jj < NJ1; ++jj) {
            const float* wr = wbase + (size_t)jj * DD + k;
            float4 wa = *(const float4*)(wr);
            float4 wb = *(const float4*)(wr + 4);
            float a = acc[jj];
            a = fmaf(wa.x, m0, a); a = fmaf(wa.y, m1, a);
            a = fmaf(wa.z, m2, a); a = fmaf(wa.w, m3, a);
            a = fmaf(wb.x, m4, a); a = fmaf(wb.y, m5, a);
            a = fmaf(wb.z, m6, a); a = fmaf(wb.w, m7, a);
            acc[jj] = a;
        }
    }
    __shared__ float sh[4][NJ1][BB];
#pragma unroll
    for (int jj = 0; jj < NJ1; ++jj) sh[wid][jj][lane] = acc[jj];
    __syncthreads();
    for (int idx = threadIdx.x; idx < NJ1 * BB; idx += 256) {
        int jj = idx >> 6, b2 = idx & 63;
        float r = (sh[0][jj][b2] + sh[1][jj][b2]) + (sh[2][jj][b2] + sh[3][jj][b2]);
        hT[(size_t)(j0 + jj) * BB + b2] = fmaxf(r, 0.0f);
    }
}

// raw[b][d] = sum_j hT[j][b] * W2[d,j]
// 192 blocks x 4 d's. 4 waves split j-range (384 each); lane = b.
__global__ __launch_bounds__(256) void k_fc2T(const float* __restrict__ hT,
                                              const float* __restrict__ W2,
                                              float* __restrict__ raw) {
    int d0 = blockIdx.x * ND2;
    int wid = threadIdx.x >> 6, lane = threadIdx.x & 63;
    const float* hp    = hT + (size_t)(wid * (TWO_D / 4)) * BB + lane;
    const float* wbase = W2 + (size_t)d0 * TWO_D + wid * (TWO_D / 4);
    float acc[ND2] = {0.f, 0.f, 0.f, 0.f};
    for (int k = 0; k < TWO_D / 4; k += 8) {     // 48 steps
        float h0 = hp[(size_t)(k + 0) * BB];
        float h1 = hp[(size_t)(k + 1) * BB];
        float h2 = hp[(size_t)(k + 2) * BB];
        float h3 = hp[(size_t)(k + 3) * BB];
        float h4 = hp[(size_t)(k + 4) * BB];
        float h5 = hp[(size_t)(k + 5) * BB];
        float h6 = hp[(size_t)(k + 6) * BB];
        float h7 = hp[(size_t)(k + 7) * BB];
#pragma unroll
        for (int dd = 0; dd < ND2; ++dd) {
            const float* wr = wbase + (size_t)dd * TWO_D + k;
            float4 wa = *(const float4*)(wr);
            float4 wb = *(const float4*)(wr + 4);
            float a = acc[dd];
            a = fmaf(wa.x, h0, a); a = fmaf(wa.y, h1, a);
            a = fmaf(wa.z, h2, a); a = fmaf(wa.w, h3, a);
            a = fmaf(wb.x, h4, a); a = fmaf(wb.y, h5, a);
            a = fmaf(wb.z, h6, a); a = fmaf(wb.w, h7, a);
            acc[dd] = a;
        }
    }
    __shared__ float sh[4][ND2][BB];
#pragma unroll
    for (int dd = 0; dd < ND2; ++dd) sh[wid][dd][lane] = acc[dd];
    __syncthreads();
    {
        int idx = threadIdx.x;                   // ND2*BB == 256 exactly
        int dd = idx >> 6, b2 = idx & 63;
        float r = (sh[0][dd][b2] + sh[1][dd][b2]) + (sh[2][dd][b2] + sh[3][dd][b2]);
        raw[(size_t)b2 * DD + d0 + dd] = r;
    }
}

// out[b,:] = raw[b,:] / ||raw[b,:]||_2  (one block per b, 256 threads)
__global__ void k_norm(const float* __restrict__ raw, float* __restrict__ out) {
    int b = blockIdx.x, t = threadIdx.x;
    float v0 = raw[b * DD + t];
    float v1 = raw[b * DD + 256 + t];
    float v2 = raw[b * DD + 512 + t];
    float s = v0 * v0 + v1 * v1 + v2 * v2;
    for (int off = 32; off; off >>= 1) s += __shfl_down(s, off);
    __shared__ float sh[4];
    __shared__ float inv_s;
    int wave = t >> 6, lane = t & 63;
    if (lane == 0) sh[wave] = s;
    __syncthreads();
    if (t == 0) inv_s = 1.0f / sqrtf(sh[0] + sh[1] + sh[2] + sh[3]);
    __syncthreads();
    float inv = inv_s;
    out[b * DD + t]       = v0 * inv;
    out[b * DD + 256 + t] = v1 * inv;
    out[b * DD + 512 + t] = v2 * inv;
}

extern "C" void kernel_launch(void* const* d_in, const int* in_sizes, int n_in,
                              void* d_out, int out_size, void* d_ws, size_t ws_size,
                              hipStream_t stream) {
    const float* emb         = (const float*)d_in[0];          // (B,L,D) f32
    const float* W1          = (const float*)d_in[1];          // (2D,D) f32
    const float* W2          = (const float*)d_in[2];          // (D,2D) f32
    const unsigned int* mask = (const unsigned int*)d_in[3];   // (B,T) bool as int32

    char* ws = (char*)d_ws;
    float* partial = (float*)(ws + OFF_PARTIAL);
    int*   lenb    = (int*)(ws + OFF_LEN);
    float* meanT   = (float*)(ws + OFF_MEANT);
    float* hT      = (float*)(ws + OFF_HT);
    float* raw     = (float*)(ws + OFF_RAW);
    float* out     = (float*)d_out;

    k_partial<<<BB * NCH, 192, 0, stream>>>(emb, mask, partial, lenb);
    k_meanT<<<192, 64, 0, stream>>>(partial, lenb, meanT);
    k_fc1T<<<TWO_D / NJ1, 256, 0, stream>>>(meanT, W1, hT);
    k_fc2T<<<DD / ND2, 256, 0, stream>>>(hT, W2, raw);
    k_norm<<<BB, 256, 0, stream>>>(raw, out);
}

// Round 16
// 78.920 us; speedup vs baseline: 1.9250x; 1.0229x over previous
//
#include <hip/hip_runtime.h>

// Problem constants (match reference)
#define BB 64
#define LL 1500
#define DD 768
#define TT 240000
#define BIN 160          // raw-time positions per bin
#define NCH 25           // L-chunks for deterministic two-stage reduce
#define LCH 60           // LL / NCH (unroll-10 divides evenly)
#define TWO_D 1536
#define NJ1 8            // j-tile per fc1 block
#define ND2 4            // d-tile per fc2 block

// ---------------- workspace layout (bytes) ----------------
#define OFF_PARTIAL 0          // BB*NCH*DD floats (4,915,200 B)
#define OFF_LEN     4915200    // BB ints (256 B)
#define OFF_MEANT   4915456    // DD*BB floats     (196,608 B)  meanT[d][b]
#define OFF_HT      5112064    // TWO_D*BB floats  (393,216 B)  hT[j][b]
#define OFF_RAW     5505280    // BB*DD floats     (196,608 B)  raw[b][d]

// k_partial: fused length-search + embedding streamer (R11 structure).
__global__ __launch_bounds__(192) void k_partial(const float* __restrict__ emb,
                                                 const unsigned int* __restrict__ mask,
                                                 float* __restrict__ partial,
                                                 int* __restrict__ lenb) {
    int w = blockIdx.x;                  // 0..BB*NCH-1, c fastest
    int b = w / NCH, c = w % NCH, t = threadIdx.x;
    int lane = t & 63;

    // wave-parallel 64-ary search for len[b] (mask is a monotone suffix)
    int lo = TT / 2, hi = TT;
    while (hi > lo) {
        int step = (hi - lo + 63) / 64;  // ceil
        int p = lo + lane * step;
        unsigned int v = (p >= hi) ? 1u : mask[(size_t)b * TT + p];
        unsigned long long bal = __ballot(v != 0u);
        int f = __ffsll((unsigned long long)bal) - 1;   // first 'True' lane
        if (f < 0) {
            lo = lo + 63 * step + 1;
            if (lo > hi) lo = hi;
        } else {
            int new_hi = lo + f * step;
            int new_lo = (f == 0) ? lo : (lo + (f - 1) * step + 1);
            lo = new_lo;
            hi = (new_hi < hi) ? new_hi : hi;
        }
    }
    int len = lo;
    if (c == 0 && t == 0) lenb[b] = len;

    int fl = len / BIN;                  // total valid bins for this b
    int n = fl - c * LCH;
    n = (n < 0) ? 0 : ((n > LCH) ? LCH : n);

    float* pout = partial + (size_t)w * DD + 4 * t;
    if (n == 0) {
        float4 z = {0.f, 0.f, 0.f, 0.f};
        *(float4*)pout = z;
        return;
    }

    const float* ebase = emb + ((size_t)b * LL + c * LCH) * DD + 4 * t;
    float4 acc = {0.f, 0.f, 0.f, 0.f};
    if (n == LCH) {
        // fast path: all 60 rows valid -- pure streaming adds
        for (int i0 = 0; i0 < LCH; i0 += 10) {
#pragma unroll
            for (int j = 0; j < 10; ++j) {       // 10 loads in flight
                float4 v = *(const float4*)(ebase + (size_t)(i0 + j) * DD);
                acc.x += v.x; acc.y += v.y; acc.z += v.z; acc.w += v.w;
            }
        }
    } else {
        // boundary chunk (<=1 per b): flag-FMA, rounded to multiple of 5
        int nr = ((n + 4) / 5) * 5;
        for (int i0 = 0; i0 < nr; i0 += 5) {
#pragma unroll
            for (int j = 0; j < 5; ++j) {
                int i = i0 + j;
                float4 v = *(const float4*)(ebase + (size_t)i * DD);
                float f = (i < n) ? 1.0f : 0.0f; // {0,1} -> exact
                acc.x = fmaf(f, v.x, acc.x);
                acc.y = fmaf(f, v.y, acc.y);
                acc.z = fmaf(f, v.z, acc.z);
                acc.w = fmaf(f, v.w, acc.w);
            }
        }
    }
    *(float4*)pout = acc;
}

// meanT[d][b] = (sum_c partial[b,c,d]) / (len[b]/BIN)
// 192 blocks (3 slabs per b) x 64 threads; thread owns one float4 column.
__global__ void k_meanT(const float* __restrict__ partial,
                        const int* __restrict__ lenb,
                        float* __restrict__ meanT) {
    int bid = blockIdx.x;
    int b = bid / 3, slab = bid % 3;
    int q = slab * 64 + threadIdx.x;         // float4 index over d (0..191)
    float cnt = (float)(lenb[b] / BIN);      // >= 750 > 0 by construction
    const float4* pb = (const float4*)(partial + (size_t)b * NCH * DD) + q;
    float4 s = {0.f, 0.f, 0.f, 0.f};
#pragma unroll 5
    for (int c = 0; c < NCH; ++c) {
        float4 v = pb[(size_t)c * (DD / 4)];
        s.x += v.x; s.y += v.y; s.z += v.z; s.w += v.w;
    }
    float inv = 1.0f / cnt;
    int d = 4 * q;
    meanT[(size_t)(d + 0) * BB + b] = s.x * inv;
    meanT[(size_t)(d + 1) * BB + b] = s.y * inv;
    meanT[(size_t)(d + 2) * BB + b] = s.z * inv;
    meanT[(size_t)(d + 3) * BB + b] = s.w * inv;
}

// hT[j][b] = relu( sum_d meanT[d][b] * W1[j,d] )
// 192 blocks x 8 j's. 4 waves split d-range (192 each); lane = b.
__global__ __launch_bounds__(256) void k_fc1T(const float* __restrict__ meanT,
                                              const float* __restrict__ W1,
                                              float* __restrict__ hT) {
    int j0 = blockIdx.x * NJ1;
    int wid = threadIdx.x >> 6, lane = threadIdx.x & 63;
    const float* mp    = meanT + (size_t)(wid * (DD / 4)) * BB + lane;
    const float* wbase = W1 + (size_t)j0 * DD + wid * (DD / 4);
    float acc[NJ1] = {0.f, 0.f, 0.f, 0.f, 0.f, 0.f, 0.f, 0.f};
    for (int k = 0; k < DD / 4; k += 8) {        // 24 steps
        float m0 = mp[(size_t)(k + 0) * BB];
        float m1 = mp[(size_t)(k + 1) * BB];
        float m2 = mp[(size_t)(k + 2) * BB];
        float m3 = mp[(size_t)(k + 3) * BB];
        float m4 = mp[(size_t)(k + 4) * BB];
        float m5 = mp[(size_t)(k + 5) * BB];
        float m6 = mp[(size_t)(k + 6) * BB];
        float m7 = mp[(size_t)(k + 7) * BB];
#pragma unroll
        for (int jj = 0; jj < NJ1; ++jj) {
            const float* wr = wbase + (size_t)jj * DD + k;
            float4 wa = *(const float4*)(wr);
            float4 wb = *(const float4*)(wr + 4);
            float a = acc[jj];
            a = fmaf(wa.x, m0, a); a = fmaf(wa.y, m1, a);
            a = fmaf(wa.z, m2, a); a = fmaf(wa.w, m3, a);
            a = fmaf(wb.x, m4, a); a = fmaf(wb.y, m5, a);
            a = fmaf(wb.z, m6, a); a = fmaf(wb.w, m7, a);
            acc[jj] = a;
        }
    }
    __shared__ float sh[4][NJ1][BB];
#pragma unroll
    for (int jj = 0; jj < NJ1; ++jj) sh[wid][jj][lane] = acc[jj];
    __syncthreads();
    for (int idx = threadIdx.x; idx < NJ1 * BB; idx += 256) {
        int jj = idx >> 6, b2 = idx & 63;
        float r = (sh[0][jj][b2] + sh[1][jj][b2]) + (sh[2][jj][b2] + sh[3][jj][b2]);
        hT[(size_t)(j0 + jj) * BB + b2] = fmaxf(r, 0.0f);
    }
}

// raw[b][d] = sum_j hT[j][b] * W2[d,j]
// 192 blocks x 4 d's. 4 waves split j-range (384 each); lane = b.
__global__ __launch_bounds__(256) void k_fc2T(const float* __restrict__ hT,
                                              const float* __restrict__ W2,
                                              float* __restrict__ raw) {
    int d0 = blockIdx.x * ND2;
    int wid = threadIdx.x >> 6, lane = threadIdx.x & 63;
    const float* hp    = hT + (size_t)(wid * (TWO_D / 4)) * BB + lane;
    const float* wbase = W2 + (size_t)d0 * TWO_D + wid * (TWO_D / 4);
    float acc[ND2] = {0.f, 0.f, 0.f, 0.f};
    for (int k = 0; k < TWO_D / 4; k += 8) {     // 48 steps
        float h0 = hp[(size_t)(k + 0) * BB];
        float h1 = hp[(size_t)(k + 1) * BB];
        float h2 = hp[(size_t)(k + 2) * BB];
        float h3 = hp[(size_t)(k + 3) * BB];
        float h4 = hp[(size_t)(k + 4) * BB];
        float h5 = hp[(size_t)(k + 5) * BB];
        float h6 = hp[(size_t)(k + 6) * BB];
        float h7 = hp[(size_t)(k + 7) * BB];
#pragma unroll
        for (int dd = 0; dd < ND2; ++dd) {
            const float* wr = wbase + (size_t)dd * TWO_D + k;
            float4 wa = *(const float4*)(wr);
            float4 wb = *(const float4*)(wr + 4);
            float a = acc[dd];
            a = fmaf(wa.x, h0, a); a = fmaf(wa.y, h1, a);
            a = fmaf(wa.z, h2, a); a = fmaf(wa.w, h3, a);
            a = fmaf(wb.x, h4, a); a = fmaf(wb.y, h5, a);
            a = fmaf(wb.z, h6, a); a = fmaf(wb.w, h7, a);
            acc[dd] = a;
        }
    }
    __shared__ float sh[4][ND2][BB];
#pragma unroll
    for (int dd = 0; dd < ND2; ++dd) sh[wid][dd][lane] = acc[dd];
    __syncthreads();
    {
        int idx = threadIdx.x;                   // ND2*BB == 256 exactly
        int dd = idx >> 6, b2 = idx & 63;
        float r = (sh[0][dd][b2] + sh[1][dd][b2]) + (sh[2][dd][b2] + sh[3][dd][b2]);
        raw[(size_t)b2 * DD + d0 + dd] = r;
    }
}

// out[b,:] = raw[b,:] / ||raw[b,:]||_2  (one block per b, 256 threads)
__global__ void k_norm(const float* __restrict__ raw, float* __restrict__ out) {
    int b = blockIdx.x, t = threadIdx.x;
    float v0 = raw[b * DD + t];
    float v1 = raw[b * DD + 256 + t];
    float v2 = raw[b * DD + 512 + t];
    float s = v0 * v0 + v1 * v1 + v2 * v2;
    for (int off = 32; off; off >>= 1) s += __shfl_down(s, off);
    __shared__ float sh[4];
    __shared__ float inv_s;
    int wave = t >> 6, lane = t & 63;
    if (lane == 0) sh[wave] = s;
    __syncthreads();
    if (t == 0) inv_s = 1.0f / sqrtf(sh[0] + sh[1] + sh[2] + sh[3]);
    __syncthreads();
    float inv = inv_s;
    out[b * DD + t]       = v0 * inv;
    out[b * DD + 256 + t] = v1 * inv;
    out[b * DD + 512 + t] = v2 * inv;
}

extern "C" void kernel_launch(void* const* d_in, const int* in_sizes, int n_in,
                              void* d_out, int out_size, void* d_ws, size_t ws_size,
                              hipStream_t stream) {
    const float* emb         = (const float*)d_in[0];          // (B,L,D) f32
    const float* W1          = (const float*)d_in[1];          // (2D,D) f32
    const float* W2          = (const float*)d_in[2];          // (D,2D) f32
    const unsigned int* mask = (const unsigned int*)d_in[3];   // (B,T) bool as int32

    char* ws = (char*)d_ws;
    float* partial = (float*)(ws + OFF_PARTIAL);
    int*   lenb    = (int*)(ws + OFF_LEN);
    float* meanT   = (float*)(ws + OFF_MEANT);
    float* hT      = (float*)(ws + OFF_HT);
    float* raw     = (float*)(ws + OFF_RAW);
    float* out     = (float*)d_out;

    k_partial<<<BB * NCH, 192, 0, stream>>>(emb, mask, partial, lenb);
    k_meanT<<<192, 64, 0, stream>>>(partial, lenb, meanT);
    k_fc1T<<<TWO_D / NJ1, 256, 0, stream>>>(meanT, W1, hT);
    k_fc2T<<<DD / ND2, 256, 0, stream>>>(hT, W2, raw);
    k_norm<<<BB, 256, 0, stream>>>(raw, out);
}